// Round 2
// baseline (436397.510 us; speedup 1.0000x reference)
//
#include <hip/hip_runtime.h>
#include <math.h>

// Propagator model: persistent cooperative kernel, layer-wavefront pipeline.
// Team l = workgroups [32l, 32l+32). WG (l, b<16) holds m[l,b] (128KB) in LDS
// for the whole run. 6 device-scope barriers per wavefront; logits for step
// w-8 run on spare (j>=16) WGs, off the recurrence critical path.

#define Hc   512
#define Lc   8
#define Kc   128
#define VDc  256
#define MHc  2048
#define Tc   512
#define Bc   16
#define VOCc 4096
#define NWG  256
#define NTHR 512

struct Params {
  const int* tok; const float* valid; const float* emb;
  const float* Wwg; const float* bwg; const float* Wfg; const float* bfg;
  const float* b1; const float* b2;
  const float* s1; const float* s2; const float* s3;
  const float* g1; const float* g2;
  const float* s_final; const float* init_mem;
  float* out;
  const float *WrkT, *WwkT, *WwvT, *WrpT, *W1T, *W2T;
  float *x0, *xin, *xp, *rkp, *rv, *ab, *t1, *t2, *tgf;
  unsigned* bar;
};

__device__ __forceinline__ float red32(float v) {
  #pragma unroll
  for (int o = 16; o > 0; o >>= 1) v += __shfl_down(v, o, 32);
  return v;
}

// Grid barrier: sense-reversing, device scope (cross-XCD safe).
__device__ void gbar(unsigned* cnt, unsigned* gen) {
  __syncthreads();
  if (threadIdx.x == 0) {
    __threadfence();  // release prior global writes
    unsigned g = __hip_atomic_load(gen, __ATOMIC_RELAXED, __HIP_MEMORY_SCOPE_AGENT);
    unsigned a = __hip_atomic_fetch_add(cnt, 1u, __ATOMIC_ACQ_REL, __HIP_MEMORY_SCOPE_AGENT);
    if (a == NWG - 1u) {
      __hip_atomic_store(cnt, 0u, __ATOMIC_RELAXED, __HIP_MEMORY_SCOPE_AGENT);
      __hip_atomic_store(gen, g + 1u, __ATOMIC_RELEASE, __HIP_MEMORY_SCOPE_AGENT);
    } else {
      while (__hip_atomic_load(gen, __ATOMIC_ACQUIRE, __HIP_MEMORY_SCOPE_AGENT) == g) {
        __builtin_amdgcn_s_sleep(1);
      }
    }
    __threadfence();  // acquire side: invalidate for subsequent reads
  }
  __syncthreads();
}

// Per-row inverse rms of a [B][H] buffer -> inv_s[16]. 512 threads, 32/row.
__device__ __forceinline__ void row_inv(const float* X, float* inv_s, int tid) {
  int r = tid >> 5, lane = tid & 31;
  float s = 0.f;
  #pragma unroll
  for (int k = 0; k < 16; ++k) { float v = X[r*Hc + lane + 32*k]; s += v*v; }
  s = red32(s);
  if (lane == 0) inv_s[r] = rsqrtf(s * (1.0f/Hc) + 1e-6f);
}

// logits[tL, :, 16 cols] = rms(x_final, s_final) @ emb^T  (spare WGs)
__device__ void do_logits(const Params& p, int l, int i, int slot, int tL,
                          int tid, float* inv_s) {
  if (tL < 0 || tL >= Tc) return;
  const float* xf = p.xin + (((size_t)(tL & 1)*Lc + 7)*Bc)*Hc;
  row_inv(xf, inv_s, tid);
  __syncthreads();
  int r = tid >> 5, lane = tid & 31;
  float iv = inv_s[r];
  float xt[16];
  #pragma unroll
  for (int k = 0; k < 16; ++k) { int h = lane + 32*k; xt[k] = xf[r*Hc + h] * iv * p.s_final[h]; }
  int col0 = (slot*128 + l*16 + i) * 16;
  for (int ci = 0; ci < 16; ++ci) {
    int c = col0 + ci;
    const float* er = p.emb + (size_t)c * Hc;
    float acc = 0.f;
    #pragma unroll
    for (int k = 0; k < 16; ++k) acc += xt[k] * er[lane + 32*k];
    acc = red32(acc);
    if (lane == 0) p.out[((size_t)tL*Bc + r)*VOCc + c] = acc;
  }
  __syncthreads();  // protect inv_s before next phase reuses it
}

__global__ void __launch_bounds__(NTHR) prop_kernel(Params p) {
  const int wg = blockIdx.x;
  const int l  = wg >> 5;
  const int j  = wg & 31;
  const int tid = threadIdx.x;
  unsigned* bcnt = p.bar + 0;
  unsigned* bgen = p.bar + 32;

  __shared__ float m_lds[Kc][VDc];   // 128 KiB: persistent memory state m[l,b]
  __shared__ float inv_s[Bc];
  __shared__ float red_s[8];
  __shared__ float sc_s;
  __shared__ float rk_s[Kc];
  __shared__ float wk_s[Kc];
  __shared__ float wv_s[VDc];
  __shared__ float err_s[VDc];
  __shared__ float ef_s[2];

  // init m from init_mem; prefill x0 for t=0
  if (j < Bc) {
    const float* src = p.init_mem + ((size_t)(l*Bc + j))*Kc*VDc;
    for (int i = tid; i < Kc*VDc; i += NTHR) (&m_lds[0][0])[i] = src[i];
  }
  if (l == 0 && j >= 16) {
    int b = j - 16;
    int tk = p.tok[b];   // token_ids[0][b]
    for (int h = tid; h < Hc; h += NTHR) p.x0[b*Hc + h] = p.emb[(size_t)tk*Hc + h];
  }
  gbar(bcnt, bgen);

  for (int w = 0; w < Tc + Lc; ++w) {
    const int t = w - l;
    const bool act = (t >= 0) && (t < Tc);
    const int pt = t & 1;
    const float* xl_in = (l == 0) ? (p.x0 + (size_t)pt*Bc*Hc)
                                  : (p.xin + ((size_t)(pt*Lc + (l-1))*Bc)*Hc);
    const int r = tid >> 5, lane = tid & 31;

    // ---- A1: rk_pre = (rms(x)*s1) @ Wrk, col-sliced over 32 WGs ----
    if (act) {
      row_inv(xl_in, inv_s, tid);
      __syncthreads();
      float iv = inv_s[r];
      float xt[16];
      #pragma unroll
      for (int k = 0; k < 16; ++k) { int h = lane + 32*k; xt[k] = xl_in[r*Hc + h] * iv * p.s1[l*Hc + h]; }
      int cb = j * 4;
      for (int ci = 0; ci < 4; ++ci) {
        int c = cb + ci;
        const float* wr = p.WrkT + ((size_t)l*Kc + c)*Hc;
        float acc = 0.f;
        #pragma unroll
        for (int k = 0; k < 16; ++k) acc += xt[k] * wr[lane + 32*k];
        acc = red32(acc);
        if (lane == 0) p.rkp[((size_t)(pt*Lc + l)*Bc + r)*Kc + c] = acc;
      }
    }
    gbar(bcnt, bgen);

    // ---- A2: rk = rms(rk_pre)*kscale; rv = m . rk  (row WGs, m in LDS) ----
    if (act && j < Bc) {
      const int b = j;
      const float* rkrow = p.rkp + ((size_t)(pt*Lc + l)*Bc + b)*Kc;
      float s = 0.f;
      if (tid < Kc) { float v = rkrow[tid]; s = v*v; }
      #pragma unroll
      for (int o = 32; o > 0; o >>= 1) s += __shfl_down(s, o, 64);
      if ((tid & 63) == 0) red_s[tid >> 6] = s;
      __syncthreads();
      if (tid == 0) {
        float tt = 0.f;
        #pragma unroll
        for (int i2 = 0; i2 < 8; ++i2) tt += red_s[i2];
        sc_s = rsqrtf(tt * (1.0f/Kc) + 1e-6f) * 0.08838834764831845f;  // *kscale
      }
      __syncthreads();
      if (tid < Kc) rk_s[tid] = rkrow[tid] * sc_s;
      __syncthreads();
      {
        int v = tid >> 1, hf = tid & 1;
        float acc = 0.f;
        #pragma unroll
        for (int kk = 0; kk < 64; ++kk) { int k = hf*64 + kk; acc += rk_s[k] * m_lds[k][v]; }
        acc += __shfl_down(acc, 1, 2);
        if (hf == 0) p.rv[((size_t)(pt*Lc + l)*Bc + b)*VDc + v] = acc;
      }
    }
    if (j >= 16) {
      if (l == 0) {           // prefetch next step's embeddings
        int tn = w + 1;
        if (tn < Tc) {
          int b = j - 16;
          int tk = p.tok[tn*Bc + b];
          for (int h = tid; h < Hc; h += NTHR)
            p.x0[((size_t)(tn & 1)*Bc + b)*Hc + h] = p.emb[(size_t)tk*Hc + h];
        }
      }
      do_logits(p, l, j - 16, 0, w - 8, tid, inv_s);
    }
    gbar(bcnt, bgen);

    // ---- B: x' = x + g1 * (rv @ Wrp), col-sliced ----
    if (act) {
      const float* rvrow = p.rv + ((size_t)(pt*Lc + l)*Bc + r)*VDc;
      float rvt[8];
      #pragma unroll
      for (int k = 0; k < 8; ++k) rvt[k] = rvrow[lane + 32*k];
      int cb = j * 16;
      for (int ci = 0; ci < 16; ++ci) {
        int c = cb + ci;
        const float* wr = p.WrpT + ((size_t)l*Hc + c)*VDc;
        float acc = 0.f;
        #pragma unroll
        for (int k = 0; k < 8; ++k) acc += rvt[k] * wr[lane + 32*k];
        acc = red32(acc);
        if (lane == 0) p.xp[((size_t)(pt*Lc + l)*Bc + r)*Hc + c] =
            xl_in[r*Hc + c] + p.g1[l*Hc + c] * acc;
      }
    }
    gbar(bcnt, bgen);

    // ---- C: a = silu(rms(x')*s2 @ W1 + b1), col-sliced (64 cols/WG) ----
    if (act) {
      const float* xprow = p.xp + ((size_t)(pt*Lc + l)*Bc)*Hc;
      row_inv(xprow, inv_s, tid);
      __syncthreads();
      float iv = inv_s[r];
      float xt[16];
      #pragma unroll
      for (int k = 0; k < 16; ++k) { int h = lane + 32*k; xt[k] = xprow[r*Hc + h] * iv * p.s2[l*Hc + h]; }
      int cb = j * 64;
      for (int ci = 0; ci < 64; ++ci) {
        int c = cb + ci;
        const float* wr = p.W1T + ((size_t)l*MHc + c)*Hc;
        float acc = 0.f;
        #pragma unroll
        for (int k = 0; k < 16; ++k) acc += xt[k] * wr[lane + 32*k];
        acc = red32(acc);
        if (lane == 0) {
          float z = acc + p.b1[l*MHc + c];
          p.ab[((size_t)(pt*Lc + l)*Bc + r)*MHc + c] = z / (1.0f + expf(-z));
        }
      }
    }
    gbar(bcnt, bgen);

    // ---- D: x'' = x' + g2 * (a @ W2 + b2), col-sliced ----
    if (act) {
      const float* arow = p.ab + ((size_t)(pt*Lc + l)*Bc + r)*MHc;
      float at[64];
      #pragma unroll
      for (int k = 0; k < 64; ++k) at[k] = arow[lane + 32*k];
      int cb = j * 16;
      for (int ci = 0; ci < 16; ++ci) {
        int c = cb + ci;
        const float* wr = p.W2T + ((size_t)l*Hc + c)*MHc;
        float acc = 0.f;
        #pragma unroll
        for (int k = 0; k < 64; ++k) acc += at[k] * wr[lane + 32*k];
        acc = red32(acc);
        if (lane == 0) {
          float xv = p.xp[((size_t)(pt*Lc + l)*Bc + r)*Hc + c];
          p.xin[((size_t)(pt*Lc + l)*Bc + r)*Hc + c] =
              xv + p.g2[l*Hc + c] * (acc + p.b2[l*Hc + c]);
        }
      }
    }
    gbar(bcnt, bgen);

    // ---- E: w = rms(x'')*s3; t1 = w@Wwk; t2 = w@Wwv; tgf = w@{Wwg,Wfg} ----
    if (act) {
      const float* xrow = p.xin + ((size_t)(pt*Lc + l)*Bc)*Hc;
      row_inv(xrow, inv_s, tid);
      __syncthreads();
      float iv = inv_s[r];
      float xt[16];
      #pragma unroll
      for (int k = 0; k < 16; ++k) { int h = lane + 32*k; xt[k] = xrow[r*Hc + h] * iv * p.s3[l*Hc + h]; }
      for (int ci = 0; ci < 12; ++ci) {
        int col = j * 12 + ci;   // 0..383: 128 -> t1, 256 -> t2
        const float* wr = (col < Kc) ? (p.WwkT + ((size_t)l*Kc + col)*Hc)
                                     : (p.WwvT + ((size_t)l*VDc + (col - Kc))*Hc);
        float acc = 0.f;
        #pragma unroll
        for (int k = 0; k < 16; ++k) acc += xt[k] * wr[lane + 32*k];
        acc = red32(acc);
        if (lane == 0) {
          if (col < Kc) p.t1[((size_t)(pt*Lc + l)*Bc + r)*Kc + col] = acc;
          else          p.t2[((size_t)(pt*Lc + l)*Bc + r)*VDc + (col - Kc)] = acc;
        }
      }
      if (j == 0) {
        float acc = 0.f, acc2 = 0.f;
        #pragma unroll
        for (int k = 0; k < 16; ++k) {
          int h = lane + 32*k;
          acc  += xt[k] * p.Wwg[l*Hc + h];
          acc2 += xt[k] * p.Wfg[l*Hc + h];
        }
        acc = red32(acc); acc2 = red32(acc2);
        if (lane == 0) {
          p.tgf[((size_t)(pt*Lc + l)*2 + 0)*Bc + r] = acc;
          p.tgf[((size_t)(pt*Lc + l)*2 + 1)*Bc + r] = acc2;
        }
      }
    }
    gbar(bcnt, bgen);

    // ---- F: wk, wv, eta, fg, vhat, err, memory update (row WGs) ----
    if (act && j < Bc) {
      const int b = j;
      const float* t1row = p.t1 + ((size_t)(pt*Lc + l)*Bc + b)*Kc;
      const float* t2row = p.t2 + ((size_t)(pt*Lc + l)*Bc + b)*VDc;
      float s = 0.f;
      if (tid < Kc) { float v = t1row[tid]; s = v*v; }
      #pragma unroll
      for (int o = 32; o > 0; o >>= 1) s += __shfl_down(s, o, 64);
      if ((tid & 63) == 0) red_s[tid >> 6] = s;
      __syncthreads();
      if (tid == 0) {
        float tt = 0.f;
        #pragma unroll
        for (int i2 = 0; i2 < 8; ++i2) tt += red_s[i2];
        sc_s = rsqrtf(tt * (1.0f/Kc) + 1e-6f) * 0.08838834764831845f;
        float te = p.tgf[((size_t)(pt*Lc + l)*2 + 0)*Bc + b];
        float tf = p.tgf[((size_t)(pt*Lc + l)*2 + 1)*Bc + b];
        ef_s[0] = 0.1f  / (1.0f + expf(-(te + p.bwg[l])));   // eta
        ef_s[1] = 0.02f / (1.0f + expf(-(tf + p.bfg[l])));   // fg
      }
      __syncthreads();
      if (tid < Kc)   wk_s[tid] = t1row[tid] * sc_s;
      if (tid >= 256) wv_s[tid - 256] = tanhf(t2row[tid - 256]);
      __syncthreads();
      {
        int v = tid >> 1, hf = tid & 1;
        float acc = 0.f;
        #pragma unroll
        for (int kk = 0; kk < 64; ++kk) { int k = hf*64 + kk; acc += wk_s[k] * m_lds[k][v]; }
        acc += __shfl_down(acc, 1, 2);
        if (hf == 0) {
          float e = wv_s[v] - acc;
          err_s[v] = fminf(1.0f, fmaxf(-1.0f, e));
        }
      }
      __syncthreads();
      const float eta = ef_s[0], fg = ef_s[1];
      const float vf = p.valid[t*Bc + b];
      const int v = tid & 255, kh = tid >> 8;
      #pragma unroll
      for (int kk = 0; kk < 64; ++kk) {
        int k = kh*64 + kk;
        float mo = m_lds[k][v];
        float nm = (1.0f - fg)*mo + eta * wk_s[k] * err_s[v];
        nm = fminf(10.0f, fmaxf(-10.0f, nm));
        m_lds[k][v] = vf*nm + (1.0f - vf)*mo;
      }
    }
    if (j >= 16) do_logits(p, l, j - 16, 1, w - 8, tid, inv_s);
    // No barrier F->A1: next A1 only reads data published >=2 barriers ago.
  }
}

// Tiled batched transpose: out[l][c][r] = in[l][r][c]
__global__ void transpose_rc(const float* __restrict__ in, float* __restrict__ out,
                             int R, int C) {
  __shared__ float tile[32][33];
  int lz = blockIdx.z;
  in  += (size_t)lz * R * C;
  out += (size_t)lz * R * C;
  int r0 = blockIdx.y * 32, c0 = blockIdx.x * 32;
  int tx = threadIdx.x, ty = threadIdx.y;
  #pragma unroll
  for (int i = ty; i < 32; i += 8) {
    int rr = r0 + i, cc = c0 + tx;
    if (rr < R && cc < C) tile[i][tx] = in[(size_t)rr*C + cc];
  }
  __syncthreads();
  #pragma unroll
  for (int i = ty; i < 32; i += 8) {
    int cc = c0 + i, rr = r0 + tx;
    if (rr < R && cc < C) out[(size_t)cc*R + rr] = tile[tx][i];
  }
}

extern "C" void kernel_launch(void* const* d_in, const int* in_sizes, int n_in,
                              void* d_out, int out_size, void* d_ws, size_t ws_size,
                              hipStream_t stream) {
  (void)in_sizes; (void)n_in; (void)out_size; (void)ws_size;
  const int*   tok   = (const int*)  d_in[0];
  const float* valid = (const float*)d_in[1];
  const float* emb   = (const float*)d_in[2];
  const float* Wrk   = (const float*)d_in[3];
  const float* Wwk   = (const float*)d_in[4];
  const float* Wwv   = (const float*)d_in[5];
  const float* Wrp   = (const float*)d_in[6];
  const float* Wwg   = (const float*)d_in[7];
  const float* bwg   = (const float*)d_in[8];
  const float* Wfg   = (const float*)d_in[9];
  const float* bfg   = (const float*)d_in[10];
  const float* W1    = (const float*)d_in[11];
  const float* b1    = (const float*)d_in[12];
  const float* W2    = (const float*)d_in[13];
  const float* b2    = (const float*)d_in[14];
  const float* s1    = (const float*)d_in[15];
  const float* s2    = (const float*)d_in[16];
  const float* s3    = (const float*)d_in[17];
  const float* g1    = (const float*)d_in[18];
  const float* g2    = (const float*)d_in[19];
  const float* s_fin = (const float*)d_in[20];
  const float* initm = (const float*)d_in[21];

  char* wsb = (char*)d_ws;
  unsigned* bar = (unsigned*)wsb;          // 256 B reserved for barrier state
  float* f = (float*)(wsb + 256);
  float* WrkT = f; f += (size_t)Lc*Kc*Hc;
  float* WwkT = f; f += (size_t)Lc*Kc*Hc;
  float* WwvT = f; f += (size_t)Lc*VDc*Hc;
  float* WrpT = f; f += (size_t)Lc*Hc*VDc;
  float* W1T  = f; f += (size_t)Lc*MHc*Hc;
  float* W2T  = f; f += (size_t)Lc*Hc*MHc;
  float* x0   = f; f += (size_t)2*Bc*Hc;
  float* xin  = f; f += (size_t)2*Lc*Bc*Hc;
  float* xp   = f; f += (size_t)2*Lc*Bc*Hc;
  float* rkp  = f; f += (size_t)2*Lc*Bc*Kc;
  float* rv   = f; f += (size_t)2*Lc*Bc*VDc;
  float* ab   = f; f += (size_t)2*Lc*Bc*MHc;
  float* t1   = f; f += (size_t)2*Lc*Bc*Kc;
  float* t2   = f; f += (size_t)2*Lc*Bc*VDc;
  float* tgf  = f; f += (size_t)2*Lc*2*Bc;

  hipMemsetAsync(d_ws, 0, 256, stream);  // barrier counters

  dim3 tb(32, 8);
  hipLaunchKernelGGL(transpose_rc, dim3(Kc/32,  Hc/32,  Lc), tb, 0, stream, Wrk, WrkT, Hc, Kc);
  hipLaunchKernelGGL(transpose_rc, dim3(Kc/32,  Hc/32,  Lc), tb, 0, stream, Wwk, WwkT, Hc, Kc);
  hipLaunchKernelGGL(transpose_rc, dim3(VDc/32, Hc/32,  Lc), tb, 0, stream, Wwv, WwvT, Hc, VDc);
  hipLaunchKernelGGL(transpose_rc, dim3(Hc/32,  VDc/32, Lc), tb, 0, stream, Wrp, WrpT, VDc, Hc);
  hipLaunchKernelGGL(transpose_rc, dim3(MHc/32, Hc/32,  Lc), tb, 0, stream, W1,  W1T,  Hc, MHc);
  hipLaunchKernelGGL(transpose_rc, dim3(Hc/32,  MHc/32, Lc), tb, 0, stream, W2,  W2T,  MHc, Hc);

  Params prm;
  prm.tok = tok; prm.valid = valid; prm.emb = emb;
  prm.Wwg = Wwg; prm.bwg = bwg; prm.Wfg = Wfg; prm.bfg = bfg;
  prm.b1 = b1; prm.b2 = b2;
  prm.s1 = s1; prm.s2 = s2; prm.s3 = s3; prm.g1 = g1; prm.g2 = g2;
  prm.s_final = s_fin; prm.init_mem = initm;
  prm.out = (float*)d_out;
  prm.WrkT = WrkT; prm.WwkT = WwkT; prm.WwvT = WwvT; prm.WrpT = WrpT;
  prm.W1T = W1T; prm.W2T = W2T;
  prm.x0 = x0; prm.xin = xin; prm.xp = xp; prm.rkp = rkp; prm.rv = rv;
  prm.ab = ab; prm.t1 = t1; prm.t2 = t2; prm.tgf = tgf;
  prm.bar = bar;

  void* args[] = { &prm };
  hipLaunchCooperativeKernel((const void*)prop_kernel, dim3(NWG), dim3(NTHR),
                             args, 0, stream);
}

// Round 4
// 193693.115 us; speedup vs baseline: 2.2530x; 2.2530x over previous
//
#include <hip/hip_runtime.h>
#include <math.h>

// Propagator model: persistent cooperative kernel, layer-wavefront pipeline.
// Team l = workgroups with (wg & 7) == l  -> one XCD per layer team.
// WG (l, j<16) holds m[l,b=j] (128KB) in LDS for the whole run.
// All matmul phases use float4 weight/activation loads with 8-16 vector
// loads in flight per lane (R2 fix: was scalar loads -> 61 GB/s convoy).
// [R4 resubmit of R3 kernel: bench infra timed out, no measurement yet.]

#define Hc   512
#define Lc   8
#define Kc   128
#define VDc  256
#define MHc  2048
#define Tc   512
#define Bc   16
#define VOCc 4096
#define NWG  256
#define NTHR 512

using f4 = __attribute__((ext_vector_type(4))) float;

struct Params {
  const int* tok; const float* valid; const float* emb;
  const float* Wwg; const float* bwg; const float* Wfg; const float* bfg;
  const float* b1; const float* b2;
  const float* s1; const float* s2; const float* s3;
  const float* g1; const float* g2;
  const float* s_final; const float* init_mem;
  float* out;
  const float *WrkT, *WwkT, *WwvT, *WrpT, *W1T, *W2T;
  float *x0, *xin, *xp, *rkp, *rv, *ab, *t1, *t2, *tgf;
  unsigned* bar;
};

__device__ __forceinline__ float hsum4(f4 a) { return a[0] + a[1] + a[2] + a[3]; }

__device__ __forceinline__ float red32(float v) {
  #pragma unroll
  for (int o = 16; o > 0; o >>= 1) v += __shfl_down(v, o, 32);
  return v;
}

// Grid barrier: sense-reversing, device scope (cross-XCD safe).
__device__ void gbar(unsigned* cnt, unsigned* gen) {
  __syncthreads();
  if (threadIdx.x == 0) {
    __threadfence();
    unsigned g = __hip_atomic_load(gen, __ATOMIC_RELAXED, __HIP_MEMORY_SCOPE_AGENT);
    unsigned a = __hip_atomic_fetch_add(cnt, 1u, __ATOMIC_ACQ_REL, __HIP_MEMORY_SCOPE_AGENT);
    if (a == NWG - 1u) {
      __hip_atomic_store(cnt, 0u, __ATOMIC_RELAXED, __HIP_MEMORY_SCOPE_AGENT);
      __hip_atomic_store(gen, g + 1u, __ATOMIC_RELEASE, __HIP_MEMORY_SCOPE_AGENT);
    } else {
      while (__hip_atomic_load(gen, __ATOMIC_ACQUIRE, __HIP_MEMORY_SCOPE_AGENT) == g) {
        __builtin_amdgcn_s_sleep(1);
      }
    }
    __threadfence();
  }
  __syncthreads();
}

// Per-row inverse rms of a [B][H] buffer -> inv_s[16]. 512 threads, 32/row.
__device__ __forceinline__ void row_inv(const float* X, float* inv_s, int tid) {
  int r = tid >> 5, lane = tid & 31;
  f4 s4 = {0.f, 0.f, 0.f, 0.f};
  #pragma unroll
  for (int q = 0; q < 4; ++q) {
    f4 v = *reinterpret_cast<const f4*>(X + r*Hc + q*128 + lane*4);
    s4 += v * v;
  }
  float s = red32(hsum4(s4));
  if (lane == 0) inv_s[r] = rsqrtf(s * (1.0f/Hc) + 1e-6f);
}

// 4-column H(=512)-length dot batch: 16 dwordx4 weight loads in flight.
__device__ __forceinline__ void dot4h(const float* w0, const float* w1,
                                      const float* w2, const float* w3,
                                      const f4 xt[4], int lane, float out[4]) {
  const float* wp[4] = {w0, w1, w2, w3};
  f4 w[4][4];
  #pragma unroll
  for (int ci = 0; ci < 4; ++ci) {
    #pragma unroll
    for (int q = 0; q < 4; ++q)
      w[ci][q] = *reinterpret_cast<const f4*>(wp[ci] + q*128 + lane*4);
  }
  #pragma unroll
  for (int ci = 0; ci < 4; ++ci) {
    f4 a = xt[0]*w[ci][0];
    a += xt[1]*w[ci][1];
    a += xt[2]*w[ci][2];
    a += xt[3]*w[ci][3];
    out[ci] = hsum4(a);
  }
}

// Load scaled x fragment: xt[q] = x[q*128+lane*4 ..+4] * iv * scale[...]
__device__ __forceinline__ void load_xt(const float* xrow, const float* srow,
                                        float iv, int lane, f4 xt[4]) {
  #pragma unroll
  for (int q = 0; q < 4; ++q) {
    f4 xv = *reinterpret_cast<const f4*>(xrow + q*128 + lane*4);
    f4 sv = *reinterpret_cast<const f4*>(srow + q*128 + lane*4);
    xt[q] = xv * iv * sv;
  }
}

// logits[tL, :, 16 cols] = rms(x_final, s_final) @ emb^T  (spare WGs)
__device__ void do_logits(const Params& p, int l, int i, int slot, int tL,
                          int tid, float* inv_s) {
  if (tL < 0 || tL >= Tc) return;
  const float* xf = p.xin + (((size_t)(tL & 1)*Lc + 7)*Bc)*Hc;
  row_inv(xf, inv_s, tid);
  __syncthreads();
  int r = tid >> 5, lane = tid & 31;
  float iv = inv_s[r];
  f4 xt[4];
  load_xt(xf + r*Hc, p.s_final, iv, lane, xt);
  int col0 = (slot*128 + l*16 + i) * 16;
  for (int cb = 0; cb < 16; cb += 4) {
    int c = col0 + cb;
    float o[4];
    dot4h(p.emb + (size_t)c*Hc, p.emb + (size_t)(c+1)*Hc,
          p.emb + (size_t)(c+2)*Hc, p.emb + (size_t)(c+3)*Hc, xt, lane, o);
    #pragma unroll
    for (int ci = 0; ci < 4; ++ci) o[ci] = red32(o[ci]);
    if (lane == 0) {
      #pragma unroll
      for (int ci = 0; ci < 4; ++ci)
        p.out[((size_t)tL*Bc + r)*VOCc + c + ci] = o[ci];
    }
  }
  __syncthreads();  // protect inv_s before next phase reuses it
}

__global__ void __launch_bounds__(NTHR) prop_kernel(Params p) {
  const int wg = blockIdx.x;
  const int l  = wg & 7;    // team -> XCD (round-robin dispatch puts all 32 on XCD l)
  const int j  = wg >> 3;
  const int tid = threadIdx.x;
  unsigned* bcnt = p.bar + 0;
  unsigned* bgen = p.bar + 32;

  __shared__ float m_lds[Kc][VDc];   // 128 KiB: persistent memory state m[l,b]
  __shared__ float inv_s[Bc];
  __shared__ float red_s[8];
  __shared__ float sc_s;
  __shared__ float rk_s[Kc];
  __shared__ float wk_s[Kc];
  __shared__ float wv_s[VDc];
  __shared__ float err_s[VDc];
  __shared__ float ef_s[2];

  // init m from init_mem; prefill x0 for t=0
  if (j < Bc) {
    const f4* src = reinterpret_cast<const f4*>(p.init_mem + ((size_t)(l*Bc + j))*Kc*VDc);
    f4* dst = reinterpret_cast<f4*>(&m_lds[0][0]);
    for (int i = tid; i < Kc*VDc/4; i += NTHR) dst[i] = src[i];
  }
  if (l == 0 && j >= 16) {
    int b = j - 16;
    int tk = p.tok[b];
    const f4* src = reinterpret_cast<const f4*>(p.emb + (size_t)tk*Hc);
    f4* dst = reinterpret_cast<f4*>(p.x0 + b*Hc);
    for (int h = tid; h < Hc/4; h += NTHR) dst[h] = src[h];
  }
  gbar(bcnt, bgen);

  for (int w = 0; w < Tc + Lc; ++w) {
    const int t = w - l;
    const bool act = (t >= 0) && (t < Tc);
    const int pt = t & 1;
    const float* xl_in = (l == 0) ? (p.x0 + (size_t)pt*Bc*Hc)
                                  : (p.xin + ((size_t)(pt*Lc + (l-1))*Bc)*Hc);
    const int r = tid >> 5, lane = tid & 31;

    // ---- A1: rk_pre = (rms(x)*s1) @ Wrk, 4 cols/WG ----
    if (act) {
      row_inv(xl_in, inv_s, tid);
      __syncthreads();
      f4 xt[4];
      load_xt(xl_in + r*Hc, p.s1 + l*Hc, inv_s[r], lane, xt);
      const float* wb = p.WrkT + (size_t)l*Kc*Hc;
      int c = j * 4;
      float o[4];
      dot4h(wb + (size_t)c*Hc, wb + (size_t)(c+1)*Hc,
            wb + (size_t)(c+2)*Hc, wb + (size_t)(c+3)*Hc, xt, lane, o);
      #pragma unroll
      for (int ci = 0; ci < 4; ++ci) o[ci] = red32(o[ci]);
      if (lane == 0) {
        #pragma unroll
        for (int ci = 0; ci < 4; ++ci)
          p.rkp[((size_t)(pt*Lc + l)*Bc + r)*Kc + c + ci] = o[ci];
      }
    }
    gbar(bcnt, bgen);

    // ---- A2: rk = rms(rk_pre)*kscale; rv = m . rk  (row WGs, m in LDS) ----
    if (act && j < Bc) {
      const int b = j;
      const float* rkrow = p.rkp + ((size_t)(pt*Lc + l)*Bc + b)*Kc;
      float s = 0.f;
      if (tid < Kc) { float v = rkrow[tid]; s = v*v; }
      #pragma unroll
      for (int o = 32; o > 0; o >>= 1) s += __shfl_down(s, o, 64);
      if ((tid & 63) == 0) red_s[tid >> 6] = s;
      __syncthreads();
      if (tid == 0) {
        float tt = 0.f;
        #pragma unroll
        for (int i2 = 0; i2 < 8; ++i2) tt += red_s[i2];
        sc_s = rsqrtf(tt * (1.0f/Kc) + 1e-6f) * 0.08838834764831845f;  // *kscale
      }
      __syncthreads();
      if (tid < Kc) rk_s[tid] = rkrow[tid] * sc_s;
      __syncthreads();
      {
        int v = tid >> 1, hf = tid & 1;
        float acc = 0.f;
        #pragma unroll
        for (int kk = 0; kk < 64; ++kk) { int k = hf*64 + kk; acc += rk_s[k] * m_lds[k][v]; }
        acc += __shfl_down(acc, 1, 2);
        if (hf == 0) p.rv[((size_t)(pt*Lc + l)*Bc + b)*VDc + v] = acc;
      }
    }
    if (j >= 16) {
      if (l == 0) {           // prefetch next step's embeddings
        int tn = w + 1;
        if (tn < Tc) {
          int b = j - 16;
          int tk = p.tok[tn*Bc + b];
          const f4* src = reinterpret_cast<const f4*>(p.emb + (size_t)tk*Hc);
          f4* dst = reinterpret_cast<f4*>(p.x0 + ((size_t)(tn & 1)*Bc + b)*Hc);
          for (int h = tid; h < Hc/4; h += NTHR) dst[h] = src[h];
        }
      }
      do_logits(p, l, j - 16, 0, w - 8, tid, inv_s);
    }
    gbar(bcnt, bgen);

    // ---- B: x' = x + g1 * (rv @ Wrp), 16 cols/WG, VD-dot ----
    if (act) {
      const float* rvrow = p.rv + ((size_t)(pt*Lc + l)*Bc + r)*VDc;
      f4 rvt[2];
      #pragma unroll
      for (int q = 0; q < 2; ++q)
        rvt[q] = *reinterpret_cast<const f4*>(rvrow + q*128 + lane*4);
      const float* wb = p.WrpT + (size_t)l*Hc*VDc;
      int cb0 = j * 16;
      for (int cb = 0; cb < 16; cb += 4) {
        int c = cb0 + cb;
        f4 wv[4][2];
        #pragma unroll
        for (int ci = 0; ci < 4; ++ci) {
          const float* wr = wb + (size_t)(c + ci)*VDc;
          #pragma unroll
          for (int q = 0; q < 2; ++q)
            wv[ci][q] = *reinterpret_cast<const f4*>(wr + q*128 + lane*4);
        }
        float o[4];
        #pragma unroll
        for (int ci = 0; ci < 4; ++ci) {
          f4 a = rvt[0]*wv[ci][0]; a += rvt[1]*wv[ci][1];
          o[ci] = red32(hsum4(a));
        }
        if (lane == 0) {
          #pragma unroll
          for (int ci = 0; ci < 4; ++ci)
            p.xp[((size_t)(pt*Lc + l)*Bc + r)*Hc + c + ci] =
                xl_in[r*Hc + c + ci] + p.g1[l*Hc + c + ci] * o[ci];
        }
      }
    }
    gbar(bcnt, bgen);

    // ---- C: a = silu(rms(x')*s2 @ W1 + b1), 64 cols/WG, H-dot ----
    if (act) {
      const float* xprow = p.xp + ((size_t)(pt*Lc + l)*Bc)*Hc;
      row_inv(xprow, inv_s, tid);
      __syncthreads();
      f4 xt[4];
      load_xt(xprow + r*Hc, p.s2 + l*Hc, inv_s[r], lane, xt);
      const float* wb = p.W1T + (size_t)l*MHc*Hc;
      int cb0 = j * 64;
      for (int cb = 0; cb < 64; cb += 4) {
        int c = cb0 + cb;
        float o[4];
        dot4h(wb + (size_t)c*Hc, wb + (size_t)(c+1)*Hc,
              wb + (size_t)(c+2)*Hc, wb + (size_t)(c+3)*Hc, xt, lane, o);
        #pragma unroll
        for (int ci = 0; ci < 4; ++ci) o[ci] = red32(o[ci]);
        if (lane == 0) {
          #pragma unroll
          for (int ci = 0; ci < 4; ++ci) {
            float z = o[ci] + p.b1[l*MHc + c + ci];
            p.ab[((size_t)(pt*Lc + l)*Bc + r)*MHc + c + ci] = z / (1.0f + expf(-z));
          }
        }
      }
    }
    gbar(bcnt, bgen);

    // ---- D: x'' = x' + g2 * (a @ W2 + b2), 16 cols/WG, MH(2048)-dot ----
    if (act) {
      const float* arow = p.ab + ((size_t)(pt*Lc + l)*Bc + r)*MHc;
      f4 at[16];
      #pragma unroll
      for (int q = 0; q < 16; ++q)
        at[q] = *reinterpret_cast<const f4*>(arow + q*128 + lane*4);
      const float* wb = p.W2T + (size_t)l*Hc*MHc;
      int cb0 = j * 16;
      for (int cb = 0; cb < 16; cb += 2) {
        const float* wr0 = wb + (size_t)(cb0 + cb)*MHc;
        const float* wr1 = wb + (size_t)(cb0 + cb + 1)*MHc;
        float acc0 = 0.f, acc1 = 0.f;
        #pragma unroll
        for (int hb = 0; hb < 2; ++hb) {
          f4 w0[8], w1[8];
          #pragma unroll
          for (int qq = 0; qq < 8; ++qq) {
            w0[qq] = *reinterpret_cast<const f4*>(wr0 + (hb*8 + qq)*128 + lane*4);
            w1[qq] = *reinterpret_cast<const f4*>(wr1 + (hb*8 + qq)*128 + lane*4);
          }
          f4 a0 = {0.f,0.f,0.f,0.f}, a1 = {0.f,0.f,0.f,0.f};
          #pragma unroll
          for (int qq = 0; qq < 8; ++qq) {
            a0 += at[hb*8 + qq] * w0[qq];
            a1 += at[hb*8 + qq] * w1[qq];
          }
          acc0 += hsum4(a0); acc1 += hsum4(a1);
        }
        acc0 = red32(acc0); acc1 = red32(acc1);
        if (lane == 0) {
          int c = cb0 + cb;
          float xv0 = p.xp[((size_t)(pt*Lc + l)*Bc + r)*Hc + c];
          float xv1 = p.xp[((size_t)(pt*Lc + l)*Bc + r)*Hc + c + 1];
          p.xin[((size_t)(pt*Lc + l)*Bc + r)*Hc + c] =
              xv0 + p.g2[l*Hc + c] * (acc0 + p.b2[l*Hc + c]);
          p.xin[((size_t)(pt*Lc + l)*Bc + r)*Hc + c + 1] =
              xv1 + p.g2[l*Hc + c + 1] * (acc1 + p.b2[l*Hc + c + 1]);
        }
      }
    }
    gbar(bcnt, bgen);

    // ---- E: w = rms(x'')*s3; t1 = w@Wwk; t2 = w@Wwv; tgf = w@{Wwg,Wfg} ----
    if (act) {
      const float* xrow = p.xin + ((size_t)(pt*Lc + l)*Bc)*Hc;
      row_inv(xrow, inv_s, tid);
      __syncthreads();
      f4 xt[4];
      load_xt(xrow + r*Hc, p.s3 + l*Hc, inv_s[r], lane, xt);
      for (int cb = 0; cb < 12; cb += 4) {
        const float* wp[4];
        int cols[4];
        #pragma unroll
        for (int ci = 0; ci < 4; ++ci) {
          int col = j*12 + cb + ci;
          cols[ci] = col;
          wp[ci] = (col < Kc) ? (p.WwkT + ((size_t)l*Kc + col)*Hc)
                              : (p.WwvT + ((size_t)l*VDc + (col - Kc))*Hc);
        }
        float o[4];
        dot4h(wp[0], wp[1], wp[2], wp[3], xt, lane, o);
        #pragma unroll
        for (int ci = 0; ci < 4; ++ci) o[ci] = red32(o[ci]);
        if (lane == 0) {
          #pragma unroll
          for (int ci = 0; ci < 4; ++ci) {
            int col = cols[ci];
            if (col < Kc) p.t1[((size_t)(pt*Lc + l)*Bc + r)*Kc + col] = o[ci];
            else          p.t2[((size_t)(pt*Lc + l)*Bc + r)*VDc + (col - Kc)] = o[ci];
          }
        }
      }
      if (j == 0) {
        f4 ag = {0.f,0.f,0.f,0.f}, af = {0.f,0.f,0.f,0.f};
        #pragma unroll
        for (int q = 0; q < 4; ++q) {
          f4 wg4 = *reinterpret_cast<const f4*>(p.Wwg + l*Hc + q*128 + lane*4);
          f4 wf4 = *reinterpret_cast<const f4*>(p.Wfg + l*Hc + q*128 + lane*4);
          ag += xt[q] * wg4;
          af += xt[q] * wf4;
        }
        float sg = red32(hsum4(ag));
        float sf = red32(hsum4(af));
        if (lane == 0) {
          p.tgf[((size_t)(pt*Lc + l)*2 + 0)*Bc + r] = sg;
          p.tgf[((size_t)(pt*Lc + l)*2 + 1)*Bc + r] = sf;
        }
      }
    }
    gbar(bcnt, bgen);

    // ---- F: wk, wv, eta, fg, vhat, err, memory update (row WGs) ----
    if (act && j < Bc) {
      const int b = j;
      const float* t1row = p.t1 + ((size_t)(pt*Lc + l)*Bc + b)*Kc;
      const float* t2row = p.t2 + ((size_t)(pt*Lc + l)*Bc + b)*VDc;
      float s = 0.f;
      if (tid < Kc) { float v = t1row[tid]; s = v*v; }
      #pragma unroll
      for (int o = 32; o > 0; o >>= 1) s += __shfl_down(s, o, 64);
      if ((tid & 63) == 0) red_s[tid >> 6] = s;
      __syncthreads();
      if (tid == 0) {
        float tt = 0.f;
        #pragma unroll
        for (int i2 = 0; i2 < 8; ++i2) tt += red_s[i2];
        sc_s = rsqrtf(tt * (1.0f/Kc) + 1e-6f) * 0.08838834764831845f;
        float te = p.tgf[((size_t)(pt*Lc + l)*2 + 0)*Bc + b];
        float tf = p.tgf[((size_t)(pt*Lc + l)*2 + 1)*Bc + b];
        ef_s[0] = 0.1f  / (1.0f + expf(-(te + p.bwg[l])));   // eta
        ef_s[1] = 0.02f / (1.0f + expf(-(tf + p.bfg[l])));   // fg
      }
      __syncthreads();
      if (tid < Kc)   wk_s[tid] = t1row[tid] * sc_s;
      if (tid >= 256) wv_s[tid - 256] = tanhf(t2row[tid - 256]);
      __syncthreads();
      {
        int v = tid >> 1, hf = tid & 1;
        float acc = 0.f;
        #pragma unroll
        for (int kk = 0; kk < 64; ++kk) { int k = hf*64 + kk; acc += wk_s[k] * m_lds[k][v]; }
        acc += __shfl_down(acc, 1, 2);
        if (hf == 0) {
          float e = wv_s[v] - acc;
          err_s[v] = fminf(1.0f, fmaxf(-1.0f, e));
        }
      }
      __syncthreads();
      const float eta = ef_s[0], fg = ef_s[1];
      const float vf = p.valid[t*Bc + b];
      const int v = tid & 255, kh = tid >> 8;
      #pragma unroll
      for (int kk = 0; kk < 64; ++kk) {
        int k = kh*64 + kk;
        float mo = m_lds[k][v];
        float nm = (1.0f - fg)*mo + eta * wk_s[k] * err_s[v];
        nm = fminf(10.0f, fmaxf(-10.0f, nm));
        m_lds[k][v] = vf*nm + (1.0f - vf)*mo;
      }
    }
    if (j >= 16) do_logits(p, l, j - 16, 1, w - 8, tid, inv_s);
    // No barrier F->A1: next A1 only reads data published >=2 barriers ago.
  }
}

// Tiled batched transpose: out[l][c][r] = in[l][r][c]
__global__ void transpose_rc(const float* __restrict__ in, float* __restrict__ out,
                             int R, int C) {
  __shared__ float tile[32][33];
  int lz = blockIdx.z;
  in  += (size_t)lz * R * C;
  out += (size_t)lz * R * C;
  int r0 = blockIdx.y * 32, c0 = blockIdx.x * 32;
  int tx = threadIdx.x, ty = threadIdx.y;
  #pragma unroll
  for (int i = ty; i < 32; i += 8) {
    int rr = r0 + i, cc = c0 + tx;
    if (rr < R && cc < C) tile[i][tx] = in[(size_t)rr*C + cc];
  }
  __syncthreads();
  #pragma unroll
  for (int i = ty; i < 32; i += 8) {
    int cc = c0 + i, rr = r0 + tx;
    if (rr < R && cc < C) out[(size_t)cc*R + rr] = tile[tx][i];
  }
}

extern "C" void kernel_launch(void* const* d_in, const int* in_sizes, int n_in,
                              void* d_out, int out_size, void* d_ws, size_t ws_size,
                              hipStream_t stream) {
  (void)in_sizes; (void)n_in; (void)out_size; (void)ws_size;
  const int*   tok   = (const int*)  d_in[0];
  const float* valid = (const float*)d_in[1];
  const float* emb   = (const float*)d_in[2];
  const float* Wrk   = (const float*)d_in[3];
  const float* Wwk   = (const float*)d_in[4];
  const float* Wwv   = (const float*)d_in[5];
  const float* Wrp   = (const float*)d_in[6];
  const float* Wwg   = (const float*)d_in[7];
  const float* bwg   = (const float*)d_in[8];
  const float* Wfg   = (const float*)d_in[9];
  const float* bfg   = (const float*)d_in[10];
  const float* W1    = (const float*)d_in[11];
  const float* b1    = (const float*)d_in[12];
  const float* W2    = (const float*)d_in[13];
  const float* b2    = (const float*)d_in[14];
  const float* s1    = (const float*)d_in[15];
  const float* s2    = (const float*)d_in[16];
  const float* s3    = (const float*)d_in[17];
  const float* g1    = (const float*)d_in[18];
  const float* g2    = (const float*)d_in[19];
  const float* s_fin = (const float*)d_in[20];
  const float* initm = (const float*)d_in[21];

  char* wsb = (char*)d_ws;
  unsigned* bar = (unsigned*)wsb;          // 256 B reserved for barrier state
  float* f = (float*)(wsb + 256);
  float* WrkT = f; f += (size_t)Lc*Kc*Hc;
  float* WwkT = f; f += (size_t)Lc*Kc*Hc;
  float* WwvT = f; f += (size_t)Lc*VDc*Hc;
  float* WrpT = f; f += (size_t)Lc*Hc*VDc;
  float* W1T  = f; f += (size_t)Lc*MHc*Hc;
  float* W2T  = f; f += (size_t)Lc*Hc*MHc;
  float* x0   = f; f += (size_t)2*Bc*Hc;
  float* xin  = f; f += (size_t)2*Lc*Bc*Hc;
  float* xp   = f; f += (size_t)2*Lc*Bc*Hc;
  float* rkp  = f; f += (size_t)2*Lc*Bc*Kc;
  float* rv   = f; f += (size_t)2*Lc*Bc*VDc;
  float* ab   = f; f += (size_t)2*Lc*Bc*MHc;
  float* t1   = f; f += (size_t)2*Lc*Bc*Kc;
  float* t2   = f; f += (size_t)2*Lc*Bc*VDc;
  float* tgf  = f; f += (size_t)2*Lc*2*Bc;

  hipMemsetAsync(d_ws, 0, 256, stream);  // barrier counters

  dim3 tb(32, 8);
  hipLaunchKernelGGL(transpose_rc, dim3(Kc/32,  Hc/32,  Lc), tb, 0, stream, Wrk, WrkT, Hc, Kc);
  hipLaunchKernelGGL(transpose_rc, dim3(Kc/32,  Hc/32,  Lc), tb, 0, stream, Wwk, WwkT, Hc, Kc);
  hipLaunchKernelGGL(transpose_rc, dim3(VDc/32, Hc/32,  Lc), tb, 0, stream, Wwv, WwvT, Hc, VDc);
  hipLaunchKernelGGL(transpose_rc, dim3(Hc/32,  VDc/32, Lc), tb, 0, stream, Wrp, WrpT, VDc, Hc);
  hipLaunchKernelGGL(transpose_rc, dim3(MHc/32, Hc/32,  Lc), tb, 0, stream, W1,  W1T,  Hc, MHc);
  hipLaunchKernelGGL(transpose_rc, dim3(Hc/32,  MHc/32, Lc), tb, 0, stream, W2,  W2T,  MHc, Hc);

  Params prm;
  prm.tok = tok; prm.valid = valid; prm.emb = emb;
  prm.Wwg = Wwg; prm.bwg = bwg; prm.Wfg = Wfg; prm.bfg = bfg;
  prm.b1 = b1; prm.b2 = b2;
  prm.s1 = s1; prm.s2 = s2; prm.s3 = s3; prm.g1 = g1; prm.g2 = g2;
  prm.s_final = s_fin; prm.init_mem = initm;
  prm.out = (float*)d_out;
  prm.WrkT = WrkT; prm.WwkT = WwkT; prm.WwvT = WwvT; prm.WrpT = WrpT;
  prm.W1T = W1T; prm.W2T = W2T;
  prm.x0 = x0; prm.xin = xin; prm.xp = xp; prm.rkp = rkp; prm.rv = rv;
  prm.ab = ab; prm.t1 = t1; prm.t2 = t2; prm.tgf = tgf;
  prm.bar = bar;

  void* args[] = { &prm };
  hipLaunchCooperativeKernel((const void*)prop_kernel, dim3(NWG), dim3(NTHR),
                             args, 0, stream);
}

// Round 6
// 149344.873 us; speedup vs baseline: 2.9221x; 1.2970x over previous
//
#include <hip/hip_runtime.h>
#include <math.h>

// Propagator model: persistent cooperative kernel, layer-wavefront pipeline,
// WEIGHT-STATIONARY registers (R5/R6): each team (layer) holds its 9.5MB of
// weights in the 32 WGs' register files (~148 f32/thread), packed per-launch.
// Matmul = k-on-lanes FMA + 64-lane shfl_xor butterfly (+ LDS-atomic combine
// where k is wave-split). m[l,b] stays in LDS on WG j<16; logits stream emb.
// [R6: resubmit of R5 (GPU acquisition timeout, never measured); host-side
//  pointer-setup cleanup only.]

#define Hc   512
#define Lc   8
#define Kc   128
#define VDc  256
#define MHc  2048
#define Tc   512
#define Bc   16
#define VOCc 4096
#define NWG  256
#define NTHR 512

using f4 = __attribute__((ext_vector_type(4))) float;

struct Params {
  const int* tok; const float* valid; const float* emb;
  const float* Wwg; const float* bwg; const float* Wfg; const float* bfg;
  const float* b1; const float* b2;
  const float* s1; const float* s2; const float* s3;
  const float* g1; const float* g2;
  const float* s_final; const float* init_mem;
  float* out;
  const f4 *fA1, *fB, *fC, *fD, *fE;   // packed weight fragments
  float *x0, *xin, *xp, *rkp, *rv, *ab, *t1, *t2, *tgf;
  unsigned* bar;
};

__device__ __forceinline__ float hsum4(f4 a) { return a[0] + a[1] + a[2] + a[3]; }

__device__ __forceinline__ float red32(float v) {
  #pragma unroll
  for (int o = 16; o > 0; o >>= 1) v += __shfl_down(v, o, 32);
  return v;
}

__device__ __forceinline__ float bfly(float v) {   // full 64-lane sum, all lanes get it
  #pragma unroll
  for (int m = 32; m > 0; m >>= 1) v += __shfl_xor(v, m, 64);
  return v;
}

// Grid barrier: sense-reversing, device scope (cross-XCD safe). R2/R4-proven.
__device__ void gbar(unsigned* cnt, unsigned* gen) {
  __syncthreads();
  if (threadIdx.x == 0) {
    __threadfence();
    unsigned g = __hip_atomic_load(gen, __ATOMIC_RELAXED, __HIP_MEMORY_SCOPE_AGENT);
    unsigned a = __hip_atomic_fetch_add(cnt, 1u, __ATOMIC_ACQ_REL, __HIP_MEMORY_SCOPE_AGENT);
    if (a == NWG - 1u) {
      __hip_atomic_store(cnt, 0u, __ATOMIC_RELAXED, __HIP_MEMORY_SCOPE_AGENT);
      __hip_atomic_store(gen, g + 1u, __ATOMIC_RELEASE, __HIP_MEMORY_SCOPE_AGENT);
    } else {
      while (__hip_atomic_load(gen, __ATOMIC_ACQUIRE, __HIP_MEMORY_SCOPE_AGENT) == g) {
        __builtin_amdgcn_s_sleep(1);
      }
    }
    __threadfence();
  }
  __syncthreads();
}

// Per-row inverse rms of a [B][H] buffer -> inv_s[16]. 512 threads, 32/row.
__device__ __forceinline__ void row_inv(const float* X, float* inv_s, int tid) {
  int r = tid >> 5, lane = tid & 31;
  f4 s4 = {0.f, 0.f, 0.f, 0.f};
  #pragma unroll
  for (int q = 0; q < 4; ++q) {
    f4 v = *reinterpret_cast<const f4*>(X + r*Hc + q*128 + lane*4);
    s4 += v * v;
  }
  float s = red32(hsum4(s4));
  if (lane == 0) inv_s[r] = rsqrtf(s * (1.0f/Hc) + 1e-6f);
}

// 4-column H(=512)-length dot batch (logits path, streamed).
__device__ __forceinline__ void dot4h(const float* w0, const float* w1,
                                      const float* w2, const float* w3,
                                      const f4 xt[4], int lane, float out[4]) {
  const float* wp[4] = {w0, w1, w2, w3};
  f4 w[4][4];
  #pragma unroll
  for (int ci = 0; ci < 4; ++ci) {
    #pragma unroll
    for (int q = 0; q < 4; ++q)
      w[ci][q] = *reinterpret_cast<const f4*>(wp[ci] + q*128 + lane*4);
  }
  #pragma unroll
  for (int ci = 0; ci < 4; ++ci) {
    f4 a = xt[0]*w[ci][0];
    a += xt[1]*w[ci][1];
    a += xt[2]*w[ci][2];
    a += xt[3]*w[ci][3];
    out[ci] = hsum4(a);
  }
}

__device__ __forceinline__ void load_xt(const float* xrow, const float* srow,
                                        float iv, int lane, f4 xt[4]) {
  #pragma unroll
  for (int q = 0; q < 4; ++q) {
    f4 xv = *reinterpret_cast<const f4*>(xrow + q*128 + lane*4);
    f4 sv = *reinterpret_cast<const f4*>(srow + q*128 + lane*4);
    xt[q] = xv * iv * sv;
  }
}

// logits[tL, :, 16 cols] = rms(x_final, s_final) @ emb^T  (spare WGs)
__device__ void do_logits(const Params& p, int l, int i, int slot, int tL,
                          int tid, float* inv_s) {
  if (tL < 0 || tL >= Tc) return;
  const float* xf = p.xin + (((size_t)(tL & 1)*Lc + 7)*Bc)*Hc;
  row_inv(xf, inv_s, tid);
  __syncthreads();
  int r = tid >> 5, lane = tid & 31;
  float iv = inv_s[r];
  f4 xt[4];
  load_xt(xf + r*Hc, p.s_final, iv, lane, xt);
  int col0 = (slot*128 + l*16 + i) * 16;
  for (int cb = 0; cb < 16; cb += 4) {
    int c = col0 + cb;
    float o[4];
    dot4h(p.emb + (size_t)c*Hc, p.emb + (size_t)(c+1)*Hc,
          p.emb + (size_t)(c+2)*Hc, p.emb + (size_t)(c+3)*Hc, xt, lane, o);
    #pragma unroll
    for (int ci = 0; ci < 4; ++ci) o[ci] = red32(o[ci]);
    if (lane == 0) {
      #pragma unroll
      for (int ci = 0; ci < 4; ++ci)
        p.out[((size_t)tL*Bc + r)*VOCc + c + ci] = o[ci];
    }
  }
  __syncthreads();
}

__global__ void __launch_bounds__(NTHR, 2) prop_kernel(Params p) {
  const int wg = blockIdx.x;
  const int l  = wg & 7;    // team -> XCD (perf heuristic only)
  const int j  = wg >> 3;
  const int tid = threadIdx.x;
  const int h = tid >> 6, s = tid & 63;   // wave, lane
  unsigned* bcnt = p.bar + 0;
  unsigned* bgen = p.bar + 32;

  __shared__ float m_lds[Kc][VDc];   // 128 KiB persistent memory state m[l,b]
  __shared__ float inv_s[Bc];
  __shared__ float red_s[8];
  __shared__ float sc_s;
  __shared__ float rk_s[Kc];
  __shared__ float wk_s[Kc];
  __shared__ float wv_s[VDc];
  __shared__ float err_s[VDc];
  __shared__ float ef_s[2];
  __shared__ float accA[64];    // A1 cross-wave combine [16r][4c]
  __shared__ float accD[256];   // D   [16r][16c]
  __shared__ float accE[192];   // E   [16r][12c]

  // ---- load weight fragments into registers (once) ----
  f4 wA, wB[2], wC[16], wD[16], wE[3], s1f, s2f0, s2f1, s3f;
  {
    size_t base = ((size_t)(l*32 + j)*8 + h);
    wA = p.fA1[base*64 + s];
    const f4* pB = p.fB + (base*2)*64 + s;
    #pragma unroll
    for (int q = 0; q < 2; ++q) wB[q] = pB[q*64];
    const f4* pC = p.fC + (base*16)*64 + s;
    #pragma unroll
    for (int q = 0; q < 16; ++q) wC[q] = pC[q*64];
    const f4* pD = p.fD + (base*16)*64 + s;
    #pragma unroll
    for (int q = 0; q < 16; ++q) wD[q] = pD[q*64];
    const f4* pE = p.fE + (base*3)*64 + s;
    #pragma unroll
    for (int q = 0; q < 3; ++q) wE[q] = pE[q*64];
    s1f  = *reinterpret_cast<const f4*>(p.s1 + l*Hc + (h>>2)*256 + s*4);
    s2f0 = *reinterpret_cast<const f4*>(p.s2 + l*Hc + s*4);
    s2f1 = *reinterpret_cast<const f4*>(p.s2 + l*Hc + 256 + s*4);
    s3f  = *reinterpret_cast<const f4*>(p.s3 + l*Hc + (h&1)*256 + s*4);
  }
  const float b1c = (s < 8) ? p.b1[l*MHc + j*64 + h*8 + s] : 0.f;

  // init m from init_mem; prefill x0 for t=0
  if (j < Bc) {
    const f4* src = reinterpret_cast<const f4*>(p.init_mem + ((size_t)(l*Bc + j))*Kc*VDc);
    f4* dst = reinterpret_cast<f4*>(&m_lds[0][0]);
    for (int i = tid; i < Kc*VDc/4; i += NTHR) dst[i] = src[i];
  }
  if (l == 0 && j >= 16) {
    int b = j - 16;
    int tk = p.tok[b];
    const f4* src = reinterpret_cast<const f4*>(p.emb + (size_t)tk*Hc);
    f4* dst = reinterpret_cast<f4*>(p.x0 + b*Hc);
    for (int hh = tid; hh < Hc/4; hh += NTHR) dst[hh] = src[hh];
  }
  gbar(bcnt, bgen);

  for (int w = 0; w < Tc + Lc; ++w) {
    const int t = w - l;
    const bool act = (t >= 0) && (t < Tc);
    const int pt = t & 1;
    const float* xl_in = (l == 0) ? (p.x0 + (size_t)pt*Bc*Hc)
                                  : (p.xin + ((size_t)(pt*Lc + (l-1))*Bc)*Hc);

    // ---- A1: rkp = (rms(x)*s1) @ Wrk. wave h: col h&3 of WG's 4, k-chunk h>>2 ----
    if (act) {
      row_inv(xl_in, inv_s, tid);
      if (tid < 64) accA[tid] = 0.f;
      __syncthreads();
      const int kb = (h>>2)*256;
      for (int r = 0; r < 16; ++r) {
        float iv = inv_s[r];
        f4 xa = *reinterpret_cast<const f4*>(xl_in + r*Hc + kb + s*4) * iv * s1f;
        f4 a = xa * wA;
        float v = bfly(hsum4(a));
        if (s == 0) atomicAdd(&accA[r*4 + (h&3)], v);
      }
      __syncthreads();
      if (tid < 64) {
        int r = tid >> 2, cw = tid & 3;
        p.rkp[((size_t)(pt*Lc + l)*Bc + r)*Kc + j*4 + cw] = accA[tid];
      }
    }
    gbar(bcnt, bgen);

    // ---- A2: rk = rms(rk_pre)*kscale; rv = m . rk  (row WGs, m in LDS) ----
    if (act && j < Bc) {
      const int b = j;
      const float* rkrow = p.rkp + ((size_t)(pt*Lc + l)*Bc + b)*Kc;
      float sq = 0.f;
      if (tid < Kc) { float v = rkrow[tid]; sq = v*v; }
      #pragma unroll
      for (int o = 32; o > 0; o >>= 1) sq += __shfl_down(sq, o, 64);
      if ((tid & 63) == 0) red_s[tid >> 6] = sq;
      __syncthreads();
      if (tid == 0) {
        float tt = 0.f;
        #pragma unroll
        for (int i2 = 0; i2 < 8; ++i2) tt += red_s[i2];
        sc_s = rsqrtf(tt * (1.0f/Kc) + 1e-6f) * 0.08838834764831845f;
      }
      __syncthreads();
      if (tid < Kc) rk_s[tid] = rkrow[tid] * sc_s;
      __syncthreads();
      {
        int v = tid >> 1, hf = tid & 1;
        float acc = 0.f;
        #pragma unroll
        for (int kk = 0; kk < 64; ++kk) { int k = hf*64 + kk; acc += rk_s[k] * m_lds[k][v]; }
        acc += __shfl_down(acc, 1, 2);
        if (hf == 0) p.rv[((size_t)(pt*Lc + l)*Bc + b)*VDc + v] = acc;
      }
    }
    if (j >= 16) {
      if (l == 0) {           // prefetch next step's embeddings
        int tn = w + 1;
        if (tn < Tc) {
          int b = j - 16;
          int tk = p.tok[tn*Bc + b];
          const f4* src = reinterpret_cast<const f4*>(p.emb + (size_t)tk*Hc);
          f4* dst = reinterpret_cast<f4*>(p.x0 + ((size_t)(tn & 1)*Bc + b)*Hc);
          for (int hh = tid; hh < Hc/4; hh += NTHR) dst[hh] = src[hh];
        }
      }
      do_logits(p, l, j - 16, 0, w - 8, tid, inv_s);
    }
    gbar(bcnt, bgen);

    // ---- B: x' = x + g1 * (rv @ Wrp). wave h: cols {2h, 2h+1} of WG's 16 ----
    if (act) {
      const float* rvt = p.rv + (size_t)(pt*Lc + l)*Bc*VDc;
      for (int r = 0; r < 16; ++r) {
        f4 xv = *reinterpret_cast<const f4*>(rvt + r*VDc + s*4);
        float res = 0.f;
        #pragma unroll
        for (int ci = 0; ci < 2; ++ci) {
          float v = bfly(hsum4(xv * wB[ci]));
          if (s == ci) res = v;
        }
        if (s < 2) {
          int c = j*16 + h*2 + s;
          p.xp[((size_t)(pt*Lc + l)*Bc + r)*Hc + c] =
              xl_in[r*Hc + c] + p.g1[l*Hc + c] * res;
        }
      }
    }
    gbar(bcnt, bgen);

    // ---- C: ab = silu(rms(x')*s2 @ W1 + b1). wave h: 8 cols, full k ----
    if (act) {
      const float* xpt = p.xp + (size_t)(pt*Lc + l)*Bc*Hc;
      row_inv(xpt, inv_s, tid);
      __syncthreads();
      #pragma unroll 2
      for (int r = 0; r < 16; ++r) {
        float iv = inv_s[r];
        f4 xa = *reinterpret_cast<const f4*>(xpt + r*Hc + s*4)       * iv * s2f0;
        f4 xb = *reinterpret_cast<const f4*>(xpt + r*Hc + 256 + s*4) * iv * s2f1;
        float res = 0.f;
        #pragma unroll
        for (int ci = 0; ci < 8; ++ci) {
          f4 a = xa * wC[ci*2] + xb * wC[ci*2+1];
          float v = bfly(hsum4(a));
          if (s == ci) res = v;
        }
        if (s < 8) {
          float z = res + b1c;
          p.ab[((size_t)(pt*Lc + l)*Bc + r)*MHc + j*64 + h*8 + s] = z / (1.f + expf(-z));
        }
      }
    }
    gbar(bcnt, bgen);

    // ---- D: x'' = x' + g2*(ab @ W2 + b2). wave h: kc=h&3, colgroup h>>2 ----
    if (act) {
      const float* abt = p.ab + (size_t)(pt*Lc + l)*Bc*MHc;
      if (tid < 256) accD[tid] = 0.f;
      __syncthreads();
      const int kb = (h&3)*512;
      #pragma unroll 2
      for (int r = 0; r < 16; ++r) {
        f4 xa = *reinterpret_cast<const f4*>(abt + r*MHc + kb + s*4);
        f4 xb = *reinterpret_cast<const f4*>(abt + r*MHc + kb + 256 + s*4);
        float res = 0.f;
        #pragma unroll
        for (int ci = 0; ci < 8; ++ci) {
          f4 a = xa * wD[ci*2] + xb * wD[ci*2+1];
          float v = bfly(hsum4(a));
          if (s == ci) res = v;
        }
        if (s < 8) atomicAdd(&accD[r*16 + (h>>2)*8 + s], res);
      }
      __syncthreads();
      if (tid < 256) {
        int r = tid >> 4, cw = tid & 15, c = j*16 + cw;
        float xv = p.xp[((size_t)(pt*Lc + l)*Bc + r)*Hc + c];
        p.xin[((size_t)(pt*Lc + l)*Bc + r)*Hc + c] =
            xv + p.g2[l*Hc + c] * (accD[tid] + p.b2[l*Hc + c]);
      }
    }
    gbar(bcnt, bgen);

    // ---- E: w = rms(x'')*s3; t1/t2 = w@{Wwk,Wwv}; tgf = w@{Wwg,Wfg} ----
    if (act) {
      const float* xrow = p.xin + (size_t)(pt*Lc + l)*Bc*Hc;
      row_inv(xrow, inv_s, tid);
      if (tid < 192) accE[tid] = 0.f;
      __syncthreads();
      const int kb = (h&1)*256;
      for (int r = 0; r < 16; ++r) {
        float iv = inv_s[r];
        f4 xa = *reinterpret_cast<const f4*>(xrow + r*Hc + kb + s*4) * iv * s3f;
        float res = 0.f;
        #pragma unroll
        for (int ci = 0; ci < 3; ++ci) {
          float v = bfly(hsum4(xa * wE[ci]));
          if (s == ci) res = v;
        }
        if (s < 3) atomicAdd(&accE[r*12 + (h>>1)*3 + s], res);
      }
      __syncthreads();
      if (tid < 192) {
        int r = tid / 12, cw = tid % 12, col = j*12 + cw;
        float v = accE[tid];
        if (col < Kc) p.t1[((size_t)(pt*Lc + l)*Bc + r)*Kc + col] = v;
        else          p.t2[((size_t)(pt*Lc + l)*Bc + r)*VDc + (col - Kc)] = v;
      }
      if (j == 0) {
        int r2 = tid >> 5, lane2 = tid & 31;
        f4 xt[4];
        load_xt(xrow + r2*Hc, p.s3 + l*Hc, inv_s[r2], lane2, xt);
        f4 ag = {0.f,0.f,0.f,0.f}, af = {0.f,0.f,0.f,0.f};
        #pragma unroll
        for (int q = 0; q < 4; ++q) {
          f4 wg4 = *reinterpret_cast<const f4*>(p.Wwg + l*Hc + q*128 + lane2*4);
          f4 wf4 = *reinterpret_cast<const f4*>(p.Wfg + l*Hc + q*128 + lane2*4);
          ag += xt[q] * wg4;
          af += xt[q] * wf4;
        }
        float sg = red32(hsum4(ag));
        float sf = red32(hsum4(af));
        if (lane2 == 0) {
          p.tgf[((size_t)(pt*Lc + l)*2 + 0)*Bc + r2] = sg;
          p.tgf[((size_t)(pt*Lc + l)*2 + 1)*Bc + r2] = sf;
        }
      }
    }
    gbar(bcnt, bgen);

    // ---- F: wk, wv, eta, fg, vhat, err, memory update (row WGs) ----
    if (act && j < Bc) {
      const int b = j;
      const float* t1row = p.t1 + ((size_t)(pt*Lc + l)*Bc + b)*Kc;
      const float* t2row = p.t2 + ((size_t)(pt*Lc + l)*Bc + b)*VDc;
      float sq = 0.f;
      if (tid < Kc) { float v = t1row[tid]; sq = v*v; }
      #pragma unroll
      for (int o = 32; o > 0; o >>= 1) sq += __shfl_down(sq, o, 64);
      if ((tid & 63) == 0) red_s[tid >> 6] = sq;
      __syncthreads();
      if (tid == 0) {
        float tt = 0.f;
        #pragma unroll
        for (int i2 = 0; i2 < 8; ++i2) tt += red_s[i2];
        sc_s = rsqrtf(tt * (1.0f/Kc) + 1e-6f) * 0.08838834764831845f;
        float te = p.tgf[((size_t)(pt*Lc + l)*2 + 0)*Bc + b];
        float tf = p.tgf[((size_t)(pt*Lc + l)*2 + 1)*Bc + b];
        ef_s[0] = 0.1f  / (1.0f + expf(-(te + p.bwg[l])));
        ef_s[1] = 0.02f / (1.0f + expf(-(tf + p.bfg[l])));
      }
      __syncthreads();
      if (tid < Kc)   wk_s[tid] = t1row[tid] * sc_s;
      if (tid >= 256) wv_s[tid - 256] = tanhf(t2row[tid - 256]);
      __syncthreads();
      {
        int v = tid >> 1, hf = tid & 1;
        float acc = 0.f;
        #pragma unroll
        for (int kk = 0; kk < 64; ++kk) { int k = hf*64 + kk; acc += wk_s[k] * m_lds[k][v]; }
        acc += __shfl_down(acc, 1, 2);
        if (hf == 0) {
          float e = wv_s[v] - acc;
          err_s[v] = fminf(1.0f, fmaxf(-1.0f, e));
        }
      }
      __syncthreads();
      const float eta = ef_s[0], fg = ef_s[1];
      const float vf = p.valid[t*Bc + b];
      const int v = tid & 255, kh = tid >> 8;
      #pragma unroll
      for (int kk = 0; kk < 64; ++kk) {
        int k = kh*64 + kk;
        float mo = m_lds[k][v];
        float nm = (1.0f - fg)*mo + eta * wk_s[k] * err_s[v];
        nm = fminf(10.0f, fmaxf(-10.0f, nm));
        m_lds[k][v] = vf*nm + (1.0f - vf)*mo;
      }
    }
    if (j >= 16) do_logits(p, l, j - 16, 1, w - 8, tid, inv_s);
    // No barrier F->A1: next A1 reads data published >=2 barriers ago.
  }
}

// ---------------- weight packing kernels (run each launch) ----------------
__global__ void pack_A1(const float* __restrict__ Wrk, f4* __restrict__ out) {
  int id = blockIdx.x*256 + threadIdx.x;            // total 131072
  int s = id & 63, h = (id>>6)&7, j = (id>>9)&31, l = id>>14;
  int col = j*4 + (h&3), k = (h>>2)*256 + s*4;
  f4 v;
  #pragma unroll
  for (int i = 0; i < 4; ++i) v[i] = Wrk[((size_t)l*Hc + k + i)*Kc + col];
  out[id] = v;
}
__global__ void pack_B(const float* __restrict__ Wrp, f4* __restrict__ out) {
  int id = blockIdx.x*256 + threadIdx.x;            // total 262144
  int s = id & 63, rf = (id>>6)&1, h = (id>>7)&7, j = (id>>10)&31, l = id>>15;
  int col = j*16 + h*2 + rf, k = s*4;
  f4 v;
  #pragma unroll
  for (int i = 0; i < 4; ++i) v[i] = Wrp[((size_t)l*VDc + k + i)*Hc + col];
  out[id] = v;
}
__global__ void pack_C(const float* __restrict__ W1, f4* __restrict__ out) {
  int id = blockIdx.x*256 + threadIdx.x;            // total 2097152
  int s = id & 63, rf = (id>>6)&15, h = (id>>10)&7, j = (id>>13)&31, l = id>>18;
  int ci = rf >> 1, q = rf & 1;
  int col = j*64 + h*8 + ci, k = q*256 + s*4;
  f4 v;
  #pragma unroll
  for (int i = 0; i < 4; ++i) v[i] = W1[((size_t)l*Hc + k + i)*MHc + col];
  out[id] = v;
}
__global__ void pack_D(const float* __restrict__ W2, f4* __restrict__ out) {
  int id = blockIdx.x*256 + threadIdx.x;            // total 2097152
  int s = id & 63, rf = (id>>6)&15, h = (id>>10)&7, j = (id>>13)&31, l = id>>18;
  int ci = rf >> 1, q = rf & 1;
  int col = j*16 + (h>>2)*8 + ci, k = (h&3)*512 + q*256 + s*4;
  f4 v;
  #pragma unroll
  for (int i = 0; i < 4; ++i) v[i] = W2[((size_t)l*MHc + k + i)*Hc + col];
  out[id] = v;
}
__global__ void pack_E(const float* __restrict__ Wwk, const float* __restrict__ Wwv,
                       f4* __restrict__ out) {
  int id = blockIdx.x*256 + threadIdx.x;            // total 393216
  int s = id & 63; int rem = id >> 6;
  int ci = rem % 3; rem /= 3;
  int h = rem & 7, j = (rem>>3)&31, l = rem>>8;
  int col = j*12 + (h>>1)*3 + ci, k = (h&1)*256 + s*4;
  f4 v;
  #pragma unroll
  for (int i = 0; i < 4; ++i)
    v[i] = (col < Kc) ? Wwk[((size_t)l*Hc + k + i)*Kc + col]
                      : Wwv[((size_t)l*Hc + k + i)*VDc + (col - Kc)];
  out[id] = v;
}

extern "C" void kernel_launch(void* const* d_in, const int* in_sizes, int n_in,
                              void* d_out, int out_size, void* d_ws, size_t ws_size,
                              hipStream_t stream) {
  (void)in_sizes; (void)n_in; (void)out_size; (void)ws_size;
  const int*   tok   = (const int*)  d_in[0];
  const float* valid = (const float*)d_in[1];
  const float* emb   = (const float*)d_in[2];
  const float* Wrk   = (const float*)d_in[3];
  const float* Wwk   = (const float*)d_in[4];
  const float* Wwv   = (const float*)d_in[5];
  const float* Wrp   = (const float*)d_in[6];
  const float* Wwg   = (const float*)d_in[7];
  const float* bwg   = (const float*)d_in[8];
  const float* Wfg   = (const float*)d_in[9];
  const float* bfg   = (const float*)d_in[10];
  const float* W1    = (const float*)d_in[11];
  const float* b1    = (const float*)d_in[12];
  const float* W2    = (const float*)d_in[13];
  const float* b2    = (const float*)d_in[14];
  const float* s1    = (const float*)d_in[15];
  const float* s2    = (const float*)d_in[16];
  const float* s3    = (const float*)d_in[17];
  const float* g1    = (const float*)d_in[18];
  const float* g2    = (const float*)d_in[19];
  const float* s_fin = (const float*)d_in[20];
  const float* initm = (const float*)d_in[21];

  char* wsb = (char*)d_ws;
  unsigned* bar = (unsigned*)wsb;          // 256 B barrier state
  float* f   = (float*)(wsb + 256);        // all bumps below in FLOAT units
  f4* fA1    = (f4*)f; f += 524288;        // 131072 f4
  f4* fB     = (f4*)f; f += 1048576;       // 262144 f4
  f4* fC     = (f4*)f; f += 8388608;       // 2097152 f4
  f4* fD     = (f4*)f; f += 8388608;       // 2097152 f4
  f4* fE     = (f4*)f; f += 1572864;       // 393216 f4
  float* x0  = f; f += (size_t)2*Bc*Hc;
  float* xin = f; f += (size_t)2*Lc*Bc*Hc;
  float* xp  = f; f += (size_t)2*Lc*Bc*Hc;
  float* rkp = f; f += (size_t)2*Lc*Bc*Kc;
  float* rv  = f; f += (size_t)2*Lc*Bc*VDc;
  float* ab  = f; f += (size_t)2*Lc*Bc*MHc;
  float* t1  = f; f += (size_t)2*Lc*Bc*Kc;
  float* t2  = f; f += (size_t)2*Lc*Bc*VDc;
  float* tgf = f; f += (size_t)2*Lc*2*Bc;

  hipMemsetAsync(d_ws, 0, 256, stream);

  hipLaunchKernelGGL(pack_A1, dim3(131072/256), dim3(256), 0, stream, Wrk, fA1);
  hipLaunchKernelGGL(pack_B,  dim3(262144/256), dim3(256), 0, stream, Wrp, fB);
  hipLaunchKernelGGL(pack_C,  dim3(2097152/256), dim3(256), 0, stream, W1, fC);
  hipLaunchKernelGGL(pack_D,  dim3(2097152/256), dim3(256), 0, stream, W2, fD);
  hipLaunchKernelGGL(pack_E,  dim3(393216/256), dim3(256), 0, stream, Wwk, Wwv, fE);

  Params prm;
  prm.tok = tok; prm.valid = valid; prm.emb = emb;
  prm.Wwg = Wwg; prm.bwg = bwg; prm.Wfg = Wfg; prm.bfg = bfg;
  prm.b1 = b1; prm.b2 = b2;
  prm.s1 = s1; prm.s2 = s2; prm.s3 = s3; prm.g1 = g1; prm.g2 = g2;
  prm.s_final = s_fin; prm.init_mem = initm;
  prm.out = (float*)d_out;
  prm.fA1 = fA1; prm.fB = fB; prm.fC = fC; prm.fD = fD; prm.fE = fE;
  prm.x0 = x0; prm.xin = xin; prm.xp = xp; prm.rkp = rkp; prm.rv = rv;
  prm.ab = ab; prm.t1 = t1; prm.t2 = t2; prm.tgf = tgf;
  prm.bar = bar;

  void* args[] = { &prm };
  hipLaunchCooperativeKernel((const void*)prop_kernel, dim3(NWG), dim3(NTHR),
                             args, 0, stream);
}